// Round 3
// baseline (240.633 us; speedup 1.0000x reference)
//
#include <hip/hip_runtime.h>
#include <cstddef>

// ---------------- problem constants ----------------
#define B_      4096
#define V_      778
#define J_      16
#define NB_     10
#define NC_     45
#define NROWS   2334      // V*3  (n = 3*v + d)
#define PM_     135       // 9*(J-1)
#define KPAD    152       // NB_ + PM_ + 1 (template) + 6 zero pad
#define NPAD    2432      // 19*128
#define KC      38        // K chunk: 152/38 = 4 exact

// ---------------- workspace layout (floats) ----------------
#define WS_JS   0                            // 480 : J_reg @ shapedirs (16,3,10)
#define WS_JT   480                          // 48  : J_reg @ v_template (16,3)
#define WS_ROT  1024                         // B*144 : rot mats (b,16,3,3)
#define WS_AC   (WS_ROT + (size_t)B_*144)    // B*152 : A_cat = [betas|pm|1|0]
#define WS_J    (WS_AC  + (size_t)B_*KPAD)   // B*48  : joints (b,16,3)
#define WS_A2   (WS_J   + (size_t)B_*48)     // B*192 : results2 (b,16,3,4)
#define WS_BT   (WS_A2  + (size_t)B_*192)    // 152*2432 : [shd|pdr|tmpl|0]^T
#define WS_VP   (WS_BT  + (size_t)KPAD*NPAD) // B*2432 : v_posed (padded)
// total = 12,527,616 floats = 50.1 MB

// =====================================================================
// Kernel 1: batch-independent hoist. JS[i,d,k] = sum_v Jreg[i,v]*shd[v,d,k]
// =====================================================================
__global__ __launch_bounds__(256) void k_js(const float* __restrict__ jreg,
                                            const float* __restrict__ shd,
                                            const float* __restrict__ tmpl,
                                            float* __restrict__ ws)
{
    int wid  = (blockIdx.x * 256 + threadIdx.x) >> 6;   // 528 waves
    int lane = threadIdx.x & 63;
    if (wid >= 528) return;
    float s = 0.f;
    if (wid < 480) {
        int i = wid / 30, rem = wid % 30, d = rem / 10, k = rem % 10;
        const float* jr = jreg + i * V_;
        for (int v = lane; v < V_; v += 64) s += jr[v] * shd[v*30 + d*10 + k];
    } else {
        int e = wid - 480, i = e / 3, d = e % 3;
        const float* jr = jreg + i * V_;
        for (int v = lane; v < V_; v += 64) s += jr[v] * tmpl[v*3 + d];
    }
    #pragma unroll
    for (int off = 32; off; off >>= 1) s += __shfl_down(s, off, 64);
    if (lane == 0) ws[wid] = s;
}

// =====================================================================
// Kernel 1b: BT[k][n] transpose-pack: rows 0..9 shapedirs, 10..144 posedirs,
// 145 template, 146..151 zero; cols >= NROWS zero.  grid (10, 152)
// =====================================================================
__global__ __launch_bounds__(256) void k_bt(const float* __restrict__ shd,
                                            const float* __restrict__ pdr,
                                            const float* __restrict__ tmpl,
                                            float* __restrict__ ws)
{
    int n = blockIdx.x * 256 + threadIdx.x;
    int k = blockIdx.y;
    if (n >= NPAD) return;
    float v = 0.f;
    if (n < NROWS) {
        if (k < NB_)            v = shd[n * NB_ + k];
        else if (k < NB_ + PM_) v = pdr[(size_t)n * PM_ + (k - NB_)];
        else if (k == 145)      v = tmpl[n];
    }
    ws[WS_BT + (size_t)k * NPAD + n] = v;
}

// =====================================================================
// Kernel 2a: per (b,joint): hand-pose matvec, rodrigues, A_cat row, joints
// =====================================================================
__global__ __launch_bounds__(256) void k_rod(const float* __restrict__ pc,
                                             const float* __restrict__ betas,
                                             const float* __restrict__ sc,   // (45,45)
                                             const float* __restrict__ hm,   // (45)
                                             float* __restrict__ ws)
{
    __shared__ float scs[NC_*45 + 45];
    for (int i = threadIdx.x; i < NC_*45 + 45; i += 256)
        scs[i] = (i < NC_*45) ? sc[i] : hm[i - NC_*45];
    __syncthreads();

    int gid = blockIdx.x * 256 + threadIdx.x;   // B*16 threads exactly
    int b = gid >> 4, i = gid & 15;
    const float* pcb = pc + b * 48;
    float* ac = ws + WS_AC + (size_t)b * KPAD;

    float a0, a1, a2;
    if (i == 0) { a0 = pcb[0]; a1 = pcb[1]; a2 = pcb[2]; }
    else {
        int col = (i - 1) * 3;
        float s0 = scs[NC_*45 + col], s1 = scs[NC_*45 + col + 1], s2 = scs[NC_*45 + col + 2];
        for (int k = 0; k < NC_; ++k) {
            float p = pcb[3 + k];
            s0 += p * scs[k*45 + col];
            s1 += p * scs[k*45 + col + 1];
            s2 += p * scs[k*45 + col + 2];
        }
        a0 = s0; a1 = s1; a2 = s2;
    }
    // rodrigues — mirror reference numerics
    float e0 = a0 + 1e-8f, e1 = a1 + 1e-8f, e2 = a2 + 1e-8f;
    float angle = sqrtf(e0*e0 + e1*e1 + e2*e2);
    float inv  = 1.f / angle;
    float half = 0.5f * angle;
    float sh = sinf(half), ch = cosf(half);
    float w = ch, x = sh * a0 * inv, y = sh * a1 * inv, z = sh * a2 * inv;
    float qn = 1.f / sqrtf(w*w + x*x + y*y + z*z);
    w *= qn; x *= qn; y *= qn; z *= qn;
    float w2 = w*w, x2 = x*x, y2 = y*y, z2 = z*z;
    float wx = w*x, wy = w*y, wz = w*z, xy = x*y, xz = x*z, yz = y*z;
    float R[9] = { w2+x2-y2-z2, 2*xy-2*wz,   2*wy+2*xz,
                   2*wz+2*xy,   w2-x2+y2-z2, 2*yz-2*wx,
                   2*xz-2*wy,   2*wx+2*yz,   w2-x2-y2+z2 };

    float* rot = ws + WS_ROT + (size_t)b*144 + i*9;
    #pragma unroll
    for (int q = 0; q < 9; ++q) rot[q] = R[q];

    if (i == 0) {
        const float* bb = betas + b * NB_;
        #pragma unroll
        for (int k = 0; k < NB_; ++k) ac[k] = bb[k];
        ac[145] = 1.f;
        #pragma unroll
        for (int k = 146; k < KPAD; ++k) ac[k] = 0.f;
    } else {
        float* pm = ac + NB_ + (i-1)*9;
        #pragma unroll
        for (int q = 0; q < 9; ++q)
            pm[q] = R[q] - ((q == 0 || q == 4 || q == 8) ? 1.f : 0.f);
    }
    // joints: j[b,i,d] = Jt[i,d] + JS[i,d,:] . betas[b,:]
    const float* bb = betas + b * NB_;
    float* jout = ws + WS_J + (size_t)b*48 + i*3;
    #pragma unroll
    for (int d = 0; d < 3; ++d) {
        const float* jsrow = ws + WS_JS + (i*3 + d) * NB_;
        float s = ws[WS_JT + i*3 + d];
        #pragma unroll
        for (int k = 0; k < NB_; ++k) s += jsrow[k] * bb[k];
        jout[d] = s;
    }
}

// =====================================================================
// Kernel 2b: kinematic chain, thread = (batch, finger, row-m).
// Rows of the 3x4 product chain are independent.  61440 threads.
// =====================================================================
__global__ __launch_bounds__(256) void k_chain(const float* __restrict__ trans,
                                               float* __restrict__ ws,
                                               float* __restrict__ out_jtr)
{
    int gid = blockIdx.x * 256 + threadIdx.x;    // exactly B*15
    int b = gid / 15, rem = gid % 15, f = rem / 3, m = rem % 3;
    const float* rot = ws + WS_ROT + (size_t)b*144;
    const float* j   = ws + WS_J   + (size_t)b*48;
    float* a2 = ws + WS_A2 + (size_t)b*192;
    float* jt = out_jtr + (size_t)b*63;
    const int INV[16] = {0,5,6,7,9,10,11,17,18,19,13,14,15,1,2,3};
    float trm = trans[b*3 + m];

    float j0x = j[0], j0y = j[1], j0z = j[2];
    float T0 = rot[m*3+0], T1 = rot[m*3+1], T2 = rot[m*3+2];
    float T3 = (m == 0) ? j0x : (m == 1) ? j0y : j0z;
    if (f == 0) {
        float corr = T0*j0x + T1*j0y + T2*j0z;
        a2[m*4+0] = T0; a2[m*4+1] = T1; a2[m*4+2] = T2; a2[m*4+3] = T3 - corr;
        jt[m] = (T3 + trm) * 1000.f;
    }
    float jpx = j0x, jpy = j0y, jpz = j0z;
    for (int s = 0; s < 3; ++s) {
        int i = f*3 + 1 + s;
        const float* R = rot + i*9;
        float jix = j[i*3], jiy = j[i*3+1], jiz = j[i*3+2];
        float d0 = jix - jpx, d1 = jiy - jpy, d2 = jiz - jpz;
        float n0 = T0*R[0] + T1*R[3] + T2*R[6];
        float n1 = T0*R[1] + T1*R[4] + T2*R[7];
        float n2 = T0*R[2] + T1*R[5] + T2*R[8];
        float n3 = T0*d0 + T1*d1 + T2*d2 + T3;
        T0 = n0; T1 = n1; T2 = n2; T3 = n3;
        float corr = T0*jix + T1*jiy + T2*jiz;
        a2[i*12 + m*4 + 0] = T0; a2[i*12 + m*4 + 1] = T1;
        a2[i*12 + m*4 + 2] = T2; a2[i*12 + m*4 + 3] = T3 - corr;
        jt[INV[i]*3 + m] = (T3 + trm) * 1000.f;
        jpx = jix; jpy = jiy; jpz = jiz;
    }
}

// =====================================================================
// Kernel 3: v_posed GEMM. vp = A_cat(4096x152) @ BT(152x2432).
// 128x128 tile, 8x8 micro (2x2 of 4x4), KC=38, LDS [kl][r] stride 128.
// =====================================================================
__global__ __launch_bounds__(256, 4) void k_vposed(float* __restrict__ ws)
{
    __shared__ float At[KC * 128];
    __shared__ float Bt[KC * 128];
    const float* A  = ws + WS_AC;
    const float* BT = ws + WS_BT;
    float* vp = ws + WS_VP;

    const int tid = threadIdx.x;
    const int n0 = blockIdx.x * 128;
    const int b0 = blockIdx.y * 128;
    const int tx = tid & 15;          // col group
    const int ty = tid >> 4;          // row group

    float acc[2][2][4][4] = {};
    for (int kc = 0; kc < KPAD; kc += KC) {
        #pragma unroll
        for (int it = 0; it < (128*KC)/256; ++it) {      // 19 iters
            int idx = it * 256 + tid;
            int kl = idx >> 7, r = idx & 127;
            At[kl*128 + r] = A[(size_t)(b0 + r) * KPAD + kc + kl];
            Bt[kl*128 + r] = BT[(size_t)(kc + kl) * NPAD + n0 + r];
        }
        __syncthreads();
        #pragma unroll 2
        for (int kl = 0; kl < KC; ++kl) {
            float4 a0 = *(const float4*)&At[kl*128 + ty*4];
            float4 a1 = *(const float4*)&At[kl*128 + 64 + ty*4];
            float4 bv0 = *(const float4*)&Bt[kl*128 + tx*4];
            float4 bv1 = *(const float4*)&Bt[kl*128 + 64 + tx*4];
            float ar[2][4] = {{a0.x,a0.y,a0.z,a0.w},{a1.x,a1.y,a1.z,a1.w}};
            float br[2][4] = {{bv0.x,bv0.y,bv0.z,bv0.w},{bv1.x,bv1.y,bv1.z,bv1.w}};
            #pragma unroll
            for (int i2 = 0; i2 < 2; ++i2)
                #pragma unroll
                for (int u = 0; u < 4; ++u)
                    #pragma unroll
                    for (int j2 = 0; j2 < 2; ++j2)
                        #pragma unroll
                        for (int vq = 0; vq < 4; ++vq)
                            acc[i2][j2][u][vq] += ar[i2][u] * br[j2][vq];
        }
        __syncthreads();
    }
    #pragma unroll
    for (int i2 = 0; i2 < 2; ++i2)
        #pragma unroll
        for (int u = 0; u < 4; ++u) {
            int row = b0 + i2*64 + ty*4 + u;
            float* dst = vp + (size_t)row * NPAD + n0;
            #pragma unroll
            for (int j2 = 0; j2 < 2; ++j2) {
                float4 o = { acc[i2][j2][u][0], acc[i2][j2][u][1],
                             acc[i2][j2][u][2], acc[i2][j2][u][3] };
                *(float4*)&dst[j2*64 + tx*4] = o;
            }
        }
}

// =====================================================================
// Kernel 4: LBS blend. A2 reads wave-uniform (blockIdx.y) -> scalar loads.
// =====================================================================
__global__ __launch_bounds__(256) void k_blend(const float* __restrict__ trans,
                                               const float* __restrict__ wts,  // (V,16)
                                               const float* __restrict__ ws,
                                               float* __restrict__ out)
{
    int b = blockIdx.y;
    int v = blockIdx.x * 256 + threadIdx.x;
    if (v >= V_) return;
    const float* a2 = ws + WS_A2 + (size_t)b * 192;   // uniform -> SGPR loads
    const float* vp = ws + WS_VP + (size_t)b * NPAD + v * 3;
    float p0 = vp[0], p1 = vp[1], p2 = vp[2];

    const float4* w4 = (const float4*)(wts + v * 16);
    float wreg[16];
    #pragma unroll
    for (int q = 0; q < 4; ++q) {
        float4 t = w4[q];
        wreg[q*4+0] = t.x; wreg[q*4+1] = t.y; wreg[q*4+2] = t.z; wreg[q*4+3] = t.w;
    }
    float T[12] = {};
    #pragma unroll
    for (int jj = 0; jj < J_; ++jj) {
        float wj = wreg[jj];
        #pragma unroll
        for (int q = 0; q < 12; ++q) T[q] += wj * a2[jj*12 + q];
    }
    float o0 = T[0]*p0 + T[1]*p1 + T[2]*p2  + T[3];
    float o1 = T[4]*p0 + T[5]*p1 + T[6]*p2  + T[7];
    float o2 = T[8]*p0 + T[9]*p1 + T[10]*p2 + T[11];

    float t0 = trans[b*3], t1 = trans[b*3+1], t2 = trans[b*3+2];
    float r0 = (o0 + t0) * 1000.f, r1 = (o1 + t1) * 1000.f, r2 = (o2 + t2) * 1000.f;

    float* vout = out + (size_t)b * NROWS + v * 3;
    vout[0] = r0; vout[1] = r1; vout[2] = r2;

    const int TIPS[5] = {745, 317, 444, 556, 673};
    const int TIPK[5] = {4, 8, 12, 16, 20};
    #pragma unroll
    for (int t = 0; t < 5; ++t) {
        if (v == TIPS[t]) {
            float* jt = out + (size_t)B_ * NROWS + (size_t)b * 63 + TIPK[t] * 3;
            jt[0] = r0; jt[1] = r1; jt[2] = r2;
        }
    }
}

// =====================================================================
extern "C" void kernel_launch(void* const* d_in, const int* in_sizes, int n_in,
                              void* d_out, int out_size, void* d_ws, size_t ws_size,
                              hipStream_t stream)
{
    const float* pc    = (const float*)d_in[0];  // (B,48)
    const float* betas = (const float*)d_in[1];  // (B,10)
    const float* trans = (const float*)d_in[2];  // (B,3)
    const float* shd   = (const float*)d_in[3];  // (V,3,10)  == (2334,10)
    const float* pdr   = (const float*)d_in[4];  // (V,3,135) == (2334,135)
    const float* tmpl  = (const float*)d_in[5];  // (V,3)
    const float* jreg  = (const float*)d_in[6];  // (16,V)
    const float* wts   = (const float*)d_in[7];  // (V,16)
    const float* sc    = (const float*)d_in[8];  // (45,45)
    const float* hm    = (const float*)d_in[9];  // (45)
    float* out = (float*)d_out;
    float* ws  = (float*)d_ws;   // needs ~50.1 MB

    hipLaunchKernelGGL(k_js,     dim3(132),         dim3(256), 0, stream, jreg, shd, tmpl, ws);
    hipLaunchKernelGGL(k_bt,     dim3(10, KPAD),    dim3(256), 0, stream, shd, pdr, tmpl, ws);
    hipLaunchKernelGGL(k_rod,    dim3(B_*16/256),   dim3(256), 0, stream, pc, betas, sc, hm, ws);
    hipLaunchKernelGGL(k_chain,  dim3(B_*15/256),   dim3(256), 0, stream, trans, ws,
                       out + (size_t)B_ * NROWS);
    hipLaunchKernelGGL(k_vposed, dim3(19, 32),      dim3(256), 0, stream, ws);
    hipLaunchKernelGGL(k_blend,  dim3(4, B_),       dim3(256), 0, stream, trans, wts, ws, out);
}